// Round 20
// baseline (138.533 us; speedup 1.0000x reference)
//
#include <hip/hip_runtime.h>

// ---------------------------------------------------------------------------
// Fused MHA block for MI355X (gfx950).
// B=2, S=2048, E=1024, H=16, D=64. f32 in/out, bf16 MFMA internally.
//
//   cvt_all:  x, {Wq,Wk,Wv,Wo} f32 -> bf16 (one dispatch, grid.y=5)
//   qkv_gemm: 128x128 BK=32, 3D grid (8,32,3); R19: double-buffered LDS,
//             ONE barrier per K-tile (R13-proven macro-step pattern).
//             Q pre-scaled by SC = D^-1/2 * log2(e).
//   attn:     R13 (frozen): 8-wave blocks, 256 q-rows, KVBLK=128, 64KB
//             double-buffered swizzled LDS, shiftless softmax, kv-split 2.
//   combine:  sum of split partials -> ctx bf16 [B,S,E]
//   out_gemm: 128x64 tile, 512 blocks (2/CU); R19: same dbuf pattern.
//
// permlane32_swap: a' = {a_lo || b_lo}, b' = {a_hi || b_hi}   (verified R2)
// ---------------------------------------------------------------------------

using u16 = unsigned short;
using u32 = unsigned int;

typedef __bf16 bf16x8 __attribute__((ext_vector_type(8)));
typedef float  f32x4  __attribute__((ext_vector_type(4)));
typedef float  f32x16 __attribute__((ext_vector_type(16)));
typedef u32    u32x4  __attribute__((ext_vector_type(4)));

constexpr int GB = 2;
constexpr int GS = 2048;
constexpr int GH = 16;
constexpr int GD = 64;
constexpr int GE = 1024;
constexpr int GM = GB * GS;      // 4096 rows
constexpr int PSTRIDE = 2048;    // floats per (q-tile, split) partial: 32 q x 64 d
constexpr float SCQ = 0.125f * 1.44269504088896f;   // D^-1/2 * log2(e), folded into Q

__device__ __forceinline__ u16 f2bf(float f) {
    u32 u = __float_as_uint(f);
    u += 0x7FFFu + ((u >> 16) & 1u);   // RTNE
    return (u16)(u >> 16);
}

__device__ __forceinline__ void plswap(u32& a, u32& b) {
#if __has_builtin(__builtin_amdgcn_permlane32_swap)
    auto r = __builtin_amdgcn_permlane32_swap(a, b, false, false);
    a = r[0]; b = r[1];
#else
    asm volatile("v_permlane32_swap_b32 %0, %1" : "+v"(a), "+v"(b));
#endif
}

__device__ __forceinline__ float xchg32(float v) {
    u32 a = __float_as_uint(v), b = a;
    plswap(a, b);
    return __uint_as_float((threadIdx.x & 32) ? a : b);
}

__device__ __forceinline__ u32 cvtpk(float lo, float hi) {
    u32 d;
    asm("v_cvt_pk_bf16_f32 %0, %1, %2" : "=v"(d) : "v"(lo), "v"(hi));
    return d;
}

// async global -> LDS, 16 B per lane (linear dest: base + lane*16)
__device__ __forceinline__ void gl_lds16(const u16* g, u16* l) {
#if __has_builtin(__builtin_amdgcn_global_load_lds)
    __builtin_amdgcn_global_load_lds(
        (const __attribute__((address_space(1))) void*)g,
        (__attribute__((address_space(3))) void*)l, 16, 0, 0);
#else
    *reinterpret_cast<uint4*>(l) = *reinterpret_cast<const uint4*>(g);
#endif
}

// ---------------------------------------------------------------- cvt kernel
__global__ void cvt_all(const float* __restrict__ x,
                        const float* __restrict__ w1, const float* __restrict__ w2,
                        const float* __restrict__ w3, const float* __restrict__ w4,
                        u16* __restrict__ ox,
                        u16* __restrict__ o1, u16* __restrict__ o2,
                        u16* __restrict__ o3, u16* __restrict__ o4) {
    const int y = blockIdx.y;
    const float* in = y == 0 ? x : y == 1 ? w1 : y == 2 ? w2 : y == 3 ? w3 : w4;
    u16* out = y == 0 ? ox : y == 1 ? o1 : y == 2 ? o2 : y == 3 ? o3 : o4;
    const int n = y == 0 ? GM * GE : GE * GE;
    int idx = blockIdx.x * blockDim.x + threadIdx.x;
    int stride = gridDim.x * blockDim.x;
    for (int i = idx * 4; i < n; i += stride * 4) {
        float4 f = *reinterpret_cast<const float4*>(in + i);
        ushort4 o;
        o.x = f2bf(f.x); o.y = f2bf(f.y); o.z = f2bf(f.z); o.w = f2bf(f.w);
        *reinterpret_cast<ushort4*>(out + i) = o;
    }
}

// ---------------------------------------------------------------- qkv GEMM
// 128x128 BK=32, 3D grid (8,32,3); double-buffered LDS, 1 barrier/K-tile.
__global__ __launch_bounds__(256)
void qkv_gemm(const u16* __restrict__ A,
              const u16* __restrict__ wq, const u16* __restrict__ wk, const u16* __restrict__ wv,
              const float* __restrict__ bq, const float* __restrict__ bk, const float* __restrict__ bv,
              u16* __restrict__ Qb, u16* __restrict__ Kb, u16* __restrict__ VTb) {
    constexpr int Kd = GE;
    __shared__ u16 As[2][4096];
    __shared__ u16 Bs[2][4096];

    const int z = blockIdx.z;
    const u16* __restrict__ Bw = z == 0 ? wq : z == 1 ? wk : wv;
    const float* __restrict__ bias = z == 0 ? bq : z == 1 ? bk : bv;
    u16* __restrict__ outp = z == 0 ? Qb : z == 1 ? Kb : VTb;
    const float oscale = z == 0 ? SCQ : 1.0f;

    const int tid = threadIdx.x;
    const int m0 = blockIdx.y * 128;
    const int n0 = blockIdx.x * 128;
    const int wave = tid >> 6, lane = tid & 63;
    const int wm = (wave >> 1) * 64, wn = (wave & 1) * 64;
    const int g = lane >> 4, rw = lane & 15;

    f32x4 acc[4][4] = {};

    auto stage = [&](int b, int kt) {
#pragma unroll
        for (int j = 0; j < 2; ++j) {
            int c = wave * 128 + j * 64 + lane;      // chunk in [0,512)
            int r = c >> 2, u = (c & 3) * 8;
            gl_lds16(&A [(size_t)(m0 + r) * Kd + kt + u], &As[b][c * 8]);
            gl_lds16(&Bw[(size_t)(n0 + r) * Kd + kt + u], &Bs[b][c * 8]);
        }
    };

    auto compute = [&](int b) {
        bf16x8 aF[4], bF[4];
#pragma unroll
        for (int mf = 0; mf < 4; ++mf)
            aF[mf] = *reinterpret_cast<const bf16x8*>(&As[b][(wm + mf * 16 + rw) * 32 + g * 8]);
#pragma unroll
        for (int nf = 0; nf < 4; ++nf)
            bF[nf] = *reinterpret_cast<const bf16x8*>(&Bs[b][(wn + nf * 16 + rw) * 32 + g * 8]);
#pragma unroll
        for (int mf = 0; mf < 4; ++mf)
#pragma unroll
            for (int nf = 0; nf < 4; ++nf)
                acc[mf][nf] = __builtin_amdgcn_mfma_f32_16x16x32_bf16(aF[mf], bF[nf], acc[mf][nf], 0, 0, 0);
    };

    stage(0, 0);
    __syncthreads();
#pragma unroll 1
    for (int kt = 0; kt < Kd; kt += 64) {
        stage(1, kt + 32);        // in flight during compute(0)
        compute(0);
        __syncthreads();          // drains stage(1) + reads of buf 0
        if (kt + 64 < Kd) stage(0, kt + 64);
        compute(1);
        __syncthreads();
    }

#pragma unroll
    for (int mf = 0; mf < 4; ++mf)
#pragma unroll
        for (int nf = 0; nf < 4; ++nf)
#pragma unroll
            for (int r = 0; r < 4; ++r) {
                int m = m0 + wm + mf * 16 + g * 4 + r;
                int n = n0 + wn + nf * 16 + rw;
                u16 hv = f2bf((acc[mf][nf][r] + bias[n]) * oscale);
                int b = m >> 11, s = m & (GS - 1);
                int h = n >> 6, d = n & 63;
                if (z == 2)
                    outp[(((size_t)(b * GH + h)) * GD + d) * GS + s] = hv;
                else
                    outp[(((size_t)(b * GH + h)) * GS + s) * GD + d] = hv;
            }
}

// ---------------------------------------------------------------- out GEMM
// 128x64 tile, 512 blocks (2/CU); double-buffered LDS, 1 barrier/K-tile.
__global__ __launch_bounds__(256)
void out_gemm(const u16* __restrict__ A, const u16* __restrict__ Bw,
              const float* __restrict__ bias, float* __restrict__ outp) {
    constexpr int Kd = GE, Nd = GE;
    __shared__ u16 As[2][4096];
    __shared__ u16 Bs[2][2048];

    const int m0 = blockIdx.y * 128;
    const int n0 = blockIdx.x * 64;

    const int tid = threadIdx.x;
    const int wave = tid >> 6, lane = tid & 63;
    const int wm = (wave >> 1) * 64, wn = (wave & 1) * 32;
    const int g = lane >> 4, rw = lane & 15;

    f32x4 acc[4][2] = {};

    auto stage = [&](int b, int kt) {
        int c = tid;
        int r = c >> 2, u = (c & 3) * 8;
        gl_lds16(&A [(size_t)(m0 + r) * Kd + kt + u], &As[b][c * 8]);
        int c2 = tid + 256;
        int r2 = c2 >> 2, u2 = (c2 & 3) * 8;
        gl_lds16(&A [(size_t)(m0 + r2) * Kd + kt + u2], &As[b][c2 * 8]);
        gl_lds16(&Bw[(size_t)(n0 + r) * Kd + kt + u], &Bs[b][c * 8]);
    };

    auto compute = [&](int b) {
        bf16x8 aF[4], bF[2];
#pragma unroll
        for (int mf = 0; mf < 4; ++mf)
            aF[mf] = *reinterpret_cast<const bf16x8*>(&As[b][(wm + mf * 16 + rw) * 32 + g * 8]);
#pragma unroll
        for (int nf = 0; nf < 2; ++nf)
            bF[nf] = *reinterpret_cast<const bf16x8*>(&Bs[b][(wn + nf * 16 + rw) * 32 + g * 8]);
#pragma unroll
        for (int mf = 0; mf < 4; ++mf)
#pragma unroll
            for (int nf = 0; nf < 2; ++nf)
                acc[mf][nf] = __builtin_amdgcn_mfma_f32_16x16x32_bf16(aF[mf], bF[nf], acc[mf][nf], 0, 0, 0);
    };

    stage(0, 0);
    __syncthreads();
#pragma unroll 1
    for (int kt = 0; kt < Kd; kt += 64) {
        stage(1, kt + 32);
        compute(0);
        __syncthreads();
        if (kt + 64 < Kd) stage(0, kt + 64);
        compute(1);
        __syncthreads();
    }

#pragma unroll
    for (int mf = 0; mf < 4; ++mf)
#pragma unroll
        for (int nf = 0; nf < 2; ++nf)
#pragma unroll
            for (int r = 0; r < 4; ++r) {
                int m = m0 + wm + mf * 16 + g * 4 + r;
                int n = n0 + wn + nf * 16 + rw;
                outp[(size_t)m * Nd + n] = acc[mf][nf][r] + bias[n];
            }
}

// ---------------------------------------------------------------- attention
// R13 (frozen): 8 waves x 32 q = 256 q-rows/block; KVBLK=128 (two 64-kv halves
// per barrier); double-buffered swizzled LDS (K tile 128x64, V tile 64x128).
template <int NSPLIT>
__global__ __launch_bounds__(512)
void attn_kernel(const u16* __restrict__ Q, const u16* __restrict__ Kp,
                 const u16* __restrict__ VT, u16* __restrict__ ctx,
                 float* __restrict__ Opart, float* __restrict__ Lpart) {
    int bh, qb, split;
    if (NSPLIT == 2) {
        const int wg = (blockIdx.x & 7) * 64 + (blockIdx.x >> 3);   // bijective, 512%8==0
        bh = wg >> 4;
        split = wg & 1;
        qb = ((wg >> 1) & 7) * 256;
    } else {
        const int wg = (blockIdx.x & 7) * 32 + (blockIdx.x >> 3);   // 256%8==0
        bh = wg >> 3;
        split = 0;
        qb = (wg & 7) * 256;
    }
    const int tid = threadIdx.x;
    const int wave = tid >> 6;      // 0..7
    const int lane = tid & 63;
    const int l31 = lane & 31;
    const int hi = (lane >> 5) & 1;
    const int q0 = qb + wave * 32;
    constexpr int KVLEN = GS / NSPLIT;
    constexpr int NT = KVLEN / 128;          // macro steps
    const int kvbase = split * KVLEN;

    const u16* __restrict__ Qbh = Q  + (size_t)bh * GS * GD;
    const u16* __restrict__ Kbh = Kp + (size_t)bh * GS * GD;
    const u16* __restrict__ Vbh = VT + (size_t)bh * GD * GS;

    __shared__ u16 sK[2][8192];
    __shared__ u16 sV[2][8192];

    bf16x8 qf[4];
#pragma unroll
    for (int s = 0; s < 4; ++s)
        qf[s] = *reinterpret_cast<const bf16x8*>(
            Qbh + (size_t)(q0 + l31) * GD + hi * 8 + 16 * s);

    f32x16 O0 = {}, O1 = {};
    float lsum = 0.f;

    const int kr0 = tid >> 3, kw0 = tid & 7;
    const u16* kSrc = Kbh + (size_t)(kvbase + kr0) * GD + ((kw0 ^ (kr0 & 7)) * 8);
    const int vr0 = tid >> 4, vw0 = tid & 15;
    const int vcol = ((vw0 & 8) | ((vw0 & 7) ^ (vr0 & 7))) * 8;
    const u16* vSrc = Vbh + (size_t)vr0 * GS + kvbase + vcol;
    u16* const dK0 = &sK[0][tid * 8];
    u16* const dK1 = &sK[1][tid * 8];
    u16* const dV0 = &sV[0][tid * 8];
    u16* const dV1 = &sV[1][tid * 8];

    auto stageTo = [&](u16* dk, u16* dv, const u16* ks, const u16* vs) {
        gl_lds16(ks,           dk);
        gl_lds16(ks + 64 * GD, dk + 4096);
        gl_lds16(vs,           dv);
        gl_lds16(vs + 32 * GS, dv + 4096);
    };

    int offK[4], offV[4];
#pragma unroll
    for (int s = 0; s < 4; ++s) {
        int sw = ((2 * s + hi) ^ (l31 & 7)) * 8;
        offK[s] = l31 * 64 + sw;
        offV[s] = l31 * 128 + sw;
    }

    auto half = [&](const u16* bK, const u16* bV) {
        f32x16 sa = {}, sb = {};
        bf16x8 ka[4], kb[4];
#pragma unroll
        for (int s = 0; s < 4; ++s) {
            ka[s] = *reinterpret_cast<const bf16x8*>(&bK[offK[s]]);
            kb[s] = *reinterpret_cast<const bf16x8*>(&bK[offK[s] + 2048]);
        }
        __builtin_amdgcn_s_setprio(1);
#pragma unroll
        for (int s = 0; s < 4; ++s) {
            sa = __builtin_amdgcn_mfma_f32_32x32x16_bf16(ka[s], qf[s], sa, 0, 0, 0);
            sb = __builtin_amdgcn_mfma_f32_32x32x16_bf16(kb[s], qf[s], sb, 0, 0, 0);
        }
        __builtin_amdgcn_s_setprio(0);

        bf16x8 vf0[4], vf1[4];
#pragma unroll
        for (int s = 0; s < 4; ++s) {
            vf0[s] = *reinterpret_cast<const bf16x8*>(&bV[offV[s]]);
            vf1[s] = *reinterpret_cast<const bf16x8*>(&bV[offV[s] + 4096]);
        }

        float pa[16], pb[16];
#pragma unroll
        for (int r = 0; r < 16; ++r) {
            pa[r] = __builtin_amdgcn_exp2f(sa[r]);
            pb[r] = __builtin_amdgcn_exp2f(sb[r]);
        }
        float s16[16];
#pragma unroll
        for (int r = 0; r < 16; ++r) s16[r] = pa[r] + pb[r];
#pragma unroll
        for (int r = 0; r < 8; ++r) s16[r] += s16[r + 8];
#pragma unroll
        for (int r = 0; r < 4; ++r) s16[r] += s16[r + 4];
        lsum += (s16[0] + s16[1]) + (s16[2] + s16[3]);

        u32 wa[8], wb[8];
#pragma unroll
        for (int i = 0; i < 8; ++i) {
            wa[i] = cvtpk(pa[2 * i], pa[2 * i + 1]);
            wb[i] = cvtpk(pb[2 * i], pb[2 * i + 1]);
        }
        plswap(wa[0], wa[2]); plswap(wa[1], wa[3]);
        plswap(wa[4], wa[6]); plswap(wa[5], wa[7]);
        plswap(wb[0], wb[2]); plswap(wb[1], wb[3]);
        plswap(wb[4], wb[6]); plswap(wb[5], wb[7]);
        u32x4 a0 = {wa[0], wa[1], wa[2], wa[3]};
        u32x4 a1 = {wa[4], wa[5], wa[6], wa[7]};
        u32x4 b0 = {wb[0], wb[1], wb[2], wb[3]};
        u32x4 b1 = {wb[4], wb[5], wb[6], wb[7]};
        bf16x8 pva0 = __builtin_bit_cast(bf16x8, a0);
        bf16x8 pva1 = __builtin_bit_cast(bf16x8, a1);
        bf16x8 pvb0 = __builtin_bit_cast(bf16x8, b0);
        bf16x8 pvb1 = __builtin_bit_cast(bf16x8, b1);

        __builtin_amdgcn_s_setprio(1);
        O0 = __builtin_amdgcn_mfma_f32_32x32x16_bf16(vf0[0], pva0, O0, 0, 0, 0);
        O0 = __builtin_amdgcn_mfma_f32_32x32x16_bf16(vf0[1], pva1, O0, 0, 0, 0);
        O0 = __builtin_amdgcn_mfma_f32_32x32x16_bf16(vf0[2], pvb0, O0, 0, 0, 0);
        O0 = __builtin_amdgcn_mfma_f32_32x32x16_bf16(vf0[3], pvb1, O0, 0, 0, 0);
        O1 = __builtin_amdgcn_mfma_f32_32x32x16_bf16(vf1[0], pva0, O1, 0, 0, 0);
        O1 = __builtin_amdgcn_mfma_f32_32x32x16_bf16(vf1[1], pva1, O1, 0, 0, 0);
        O1 = __builtin_amdgcn_mfma_f32_32x32x16_bf16(vf1[2], pvb0, O1, 0, 0, 0);
        O1 = __builtin_amdgcn_mfma_f32_32x32x16_bf16(vf1[3], pvb1, O1, 0, 0, 0);
        __builtin_amdgcn_s_setprio(0);
    };

    stageTo(dK0, dV0, kSrc, vSrc);
    kSrc += 128 * GD; vSrc += 128;
    __syncthreads();

#pragma unroll 1
    for (int t = 0; t < NT; t += 2) {
        stageTo(dK1, dV1, kSrc, vSrc);
        kSrc += 128 * GD; vSrc += 128;
        half(sK[0], sV[0]);
        half(sK[0] + 4096, sV[0] + 64);
        __syncthreads();
        if (t + 2 < NT) {
            stageTo(dK0, dV0, kSrc, vSrc);
            kSrc += 128 * GD; vSrc += 128;
        }
        half(sK[1], sV[1]);
        half(sK[1] + 4096, sV[1] + 64);
        __syncthreads();
    }

    lsum += xchg32(lsum);

    if (NSPLIT > 1) {
        const int wt = bh * 64 + (q0 >> 5);
        const size_t base = ((size_t)wt * NSPLIT + split) * PSTRIDE;
#pragma unroll
        for (int r = 0; r < 16; ++r) {
            int d = (r & 3) + 8 * (r >> 2) + 4 * hi;
            Opart[base + (size_t)d * 32 + l31]        = O0[r];
            Opart[base + (size_t)(d + 32) * 32 + l31] = O1[r];
        }
        if (hi == 0)
            Lpart[(wt * NSPLIT + split) * 32 + l31] = lsum;
    } else {
        const int bb = bh >> 4, h = bh & 15;
        const float inv = 1.0f / lsum;
        u16* crow = ctx + ((size_t)(bb * GS + q0 + l31)) * GE + h * 64;
#pragma unroll
        for (int g2 = 0; g2 < 4; ++g2) {
            ushort4 st0, st1;
            st0.x = f2bf(O0[4 * g2 + 0] * inv); st0.y = f2bf(O0[4 * g2 + 1] * inv);
            st0.z = f2bf(O0[4 * g2 + 2] * inv); st0.w = f2bf(O0[4 * g2 + 3] * inv);
            st1.x = f2bf(O1[4 * g2 + 0] * inv); st1.y = f2bf(O1[4 * g2 + 1] * inv);
            st1.z = f2bf(O1[4 * g2 + 2] * inv); st1.w = f2bf(O1[4 * g2 + 3] * inv);
            *reinterpret_cast<ushort4*>(crow + 8 * g2 + 4 * hi)      = st0;
            *reinterpret_cast<ushort4*>(crow + 32 + 8 * g2 + 4 * hi) = st1;
        }
    }
}

// ---------------------------------------------------------------- combine
template <int NSPLIT>
__global__ __launch_bounds__(256)
void combine_kernel(const float* __restrict__ Opart, const float* __restrict__ Lpart,
                    u16* __restrict__ ctx) {
    const int wt = blockIdx.x;
    const int bh = wt >> 6, bb = bh >> 4, h = bh & 15;
    const int q0 = (wt & 63) * 32;
    const int q = threadIdx.x & 31, db = threadIdx.x >> 5;
    const size_t b0 = (size_t)wt * NSPLIT * PSTRIDE;

    float lt = 0.f;
#pragma unroll
    for (int s = 0; s < NSPLIT; ++s) lt += Lpart[(wt * NSPLIT + s) * 32 + q];
    float inv = 1.f / lt;

    u16* crow = ctx + ((size_t)(bb * GS + q0 + q)) * GE + h * 64 + db * 8;
    ushort4 s0, s1;
    float o[8];
#pragma unroll
    for (int i = 0; i < 8; ++i) {
        int d = db * 8 + i;
        float acc = 0.f;
#pragma unroll
        for (int s = 0; s < NSPLIT; ++s)
            acc += Opart[b0 + (size_t)s * PSTRIDE + (size_t)d * 32 + q];
        o[i] = acc * inv;
    }
    s0.x = f2bf(o[0]); s0.y = f2bf(o[1]); s0.z = f2bf(o[2]); s0.w = f2bf(o[3]);
    s1.x = f2bf(o[4]); s1.y = f2bf(o[5]); s1.z = f2bf(o[6]); s1.w = f2bf(o[7]);
    *reinterpret_cast<ushort4*>(crow)     = s0;
    *reinterpret_cast<ushort4*>(crow + 4) = s1;
}

// ---------------------------------------------------------------- launcher
extern "C" void kernel_launch(void* const* d_in, const int* in_sizes, int n_in,
                              void* d_out, int out_size, void* d_ws, size_t ws_size,
                              hipStream_t stream) {
    (void)in_sizes; (void)n_in; (void)out_size;

    const float* x  = (const float*)d_in[0];
    const float* Wq = (const float*)d_in[1];
    const float* bq = (const float*)d_in[2];
    const float* Wk = (const float*)d_in[3];
    const float* bk = (const float*)d_in[4];
    const float* Wv = (const float*)d_in[5];
    const float* bv = (const float*)d_in[6];
    const float* Wo = (const float*)d_in[7];
    const float* bo = (const float*)d_in[8];
    float* out = (float*)d_out;

    char* ws = (char*)d_ws;
    u16* xb  = (u16*)(ws);                    // 8 MB  [4096,1024]
    u16* wqb = (u16*)(ws + (8ll  << 20));
    u16* wkb = (u16*)(ws + (10ll << 20));
    u16* wvb = (u16*)(ws + (12ll << 20));
    u16* wob = (u16*)(ws + (14ll << 20));
    u16* Qb  = (u16*)(ws + (16ll << 20));     // [B,H,S,D]
    u16* Kb  = (u16*)(ws + (24ll << 20));     // [B,H,S,D]
    u16* VTb = (u16*)(ws + (32ll << 20));     // [B,H,D,S]
    u16* ctx = (u16*)(ws + (40ll << 20));     // [B,S,E]
    float* Opart = (float*)(ws + (48ll << 20));   // 32 MB
    float* Lpart = (float*)(ws + (80ll << 20));
    const bool split2 = ws_size >= (81ll << 20);

    cvt_all<<<dim3(1024, 5), 256, 0, stream>>>(x, Wq, Wk, Wv, Wo,
                                               xb, wqb, wkb, wvb, wob);

    qkv_gemm<<<dim3(GE / 128, GM / 128, 3), 256, 0, stream>>>(
        xb, wqb, wkb, wvb, bq, bk, bv, Qb, Kb, VTb);

    if (split2) {
        attn_kernel<2><<<dim3(512), 512, 0, stream>>>(Qb, Kb, VTb, ctx, Opart, Lpart);
        combine_kernel<2><<<dim3(2048), 256, 0, stream>>>(Opart, Lpart, ctx);
    } else {
        attn_kernel<1><<<dim3(256), 512, 0, stream>>>(Qb, Kb, VTb, ctx, Opart, Lpart);
    }

    out_gemm<<<dim3(GE / 64, GM / 128), 256, 0, stream>>>(ctx, wob, bo, out);
}

// Round 21
// 120.499 us; speedup vs baseline: 1.1497x; 1.1497x over previous
//
#include <hip/hip_runtime.h>

// ---------------------------------------------------------------------------
// Fused MHA block for MI355X (gfx950).  [R15-exact — best measured 120.6 us]
// B=2, S=2048, E=1024, H=16, D=64. f32 in/out, bf16 MFMA internally.
//
//   cvt_all:  x, {Wq,Wk,Wv,Wo} f32 -> bf16 (one dispatch, grid.y=5)
//   qkv_gemm: 128x128 BK=32 linear LDS (m97 structure), 3D grid (8,32,3).
//             Q pre-scaled by SC = D^-1/2 * log2(e).
//             [refuted: BK=64+swizzle (R9), XCD swizzle (R14), transpose
//              epilogue (R16), qk/v split (R17), explicit dbuf (R19)]
//   attn:     R13: 8-wave blocks, 256 q-rows, KVBLK=128 (two 64-kv halves per
//             barrier), 64KB double-buffered swizzled LDS, shiftless softmax
//             P=exp2(S') with Q pre-scaled, kv-split 2 (gated ws>=81MB).
//   combine:  sum of split partials -> ctx bf16 [B,S,E]
//   out_gemm: 128x64 tile, 2D grid (16,32) = 512 blocks (2/CU).
//
// permlane32_swap: a' = {a_lo || b_lo}, b' = {a_hi || b_hi}   (verified R2)
// ---------------------------------------------------------------------------

using u16 = unsigned short;
using u32 = unsigned int;

typedef __bf16 bf16x8 __attribute__((ext_vector_type(8)));
typedef float  f32x4  __attribute__((ext_vector_type(4)));
typedef float  f32x16 __attribute__((ext_vector_type(16)));
typedef u32    u32x4  __attribute__((ext_vector_type(4)));

constexpr int GB = 2;
constexpr int GS = 2048;
constexpr int GH = 16;
constexpr int GD = 64;
constexpr int GE = 1024;
constexpr int GM = GB * GS;      // 4096 rows
constexpr int PSTRIDE = 2048;    // floats per (q-tile, split) partial: 32 q x 64 d
constexpr float SCQ = 0.125f * 1.44269504088896f;   // D^-1/2 * log2(e), folded into Q

__device__ __forceinline__ u16 f2bf(float f) {
    u32 u = __float_as_uint(f);
    u += 0x7FFFu + ((u >> 16) & 1u);   // RTNE
    return (u16)(u >> 16);
}

__device__ __forceinline__ void plswap(u32& a, u32& b) {
#if __has_builtin(__builtin_amdgcn_permlane32_swap)
    auto r = __builtin_amdgcn_permlane32_swap(a, b, false, false);
    a = r[0]; b = r[1];
#else
    asm volatile("v_permlane32_swap_b32 %0, %1" : "+v"(a), "+v"(b));
#endif
}

__device__ __forceinline__ float xchg32(float v) {
    u32 a = __float_as_uint(v), b = a;
    plswap(a, b);
    return __uint_as_float((threadIdx.x & 32) ? a : b);
}

__device__ __forceinline__ u32 cvtpk(float lo, float hi) {
    u32 d;
    asm("v_cvt_pk_bf16_f32 %0, %1, %2" : "=v"(d) : "v"(lo), "v"(hi));
    return d;
}

// async global -> LDS, 16 B per lane (linear dest: base + lane*16)
__device__ __forceinline__ void gl_lds16(const u16* g, u16* l) {
#if __has_builtin(__builtin_amdgcn_global_load_lds)
    __builtin_amdgcn_global_load_lds(
        (const __attribute__((address_space(1))) void*)g,
        (__attribute__((address_space(3))) void*)l, 16, 0, 0);
#else
    *reinterpret_cast<uint4*>(l) = *reinterpret_cast<const uint4*>(g);
#endif
}

// ---------------------------------------------------------------- cvt kernel
__global__ void cvt_all(const float* __restrict__ x,
                        const float* __restrict__ w1, const float* __restrict__ w2,
                        const float* __restrict__ w3, const float* __restrict__ w4,
                        u16* __restrict__ ox,
                        u16* __restrict__ o1, u16* __restrict__ o2,
                        u16* __restrict__ o3, u16* __restrict__ o4) {
    const int y = blockIdx.y;
    const float* in = y == 0 ? x : y == 1 ? w1 : y == 2 ? w2 : y == 3 ? w3 : w4;
    u16* out = y == 0 ? ox : y == 1 ? o1 : y == 2 ? o2 : y == 3 ? o3 : o4;
    const int n = y == 0 ? GM * GE : GE * GE;
    int idx = blockIdx.x * blockDim.x + threadIdx.x;
    int stride = gridDim.x * blockDim.x;
    for (int i = idx * 4; i < n; i += stride * 4) {
        float4 f = *reinterpret_cast<const float4*>(in + i);
        ushort4 o;
        o.x = f2bf(f.x); o.y = f2bf(f.y); o.z = f2bf(f.z); o.w = f2bf(f.w);
        *reinterpret_cast<ushort4*>(out + i) = o;
    }
}

// ---------------------------------------------------------------- qkv GEMM
// 128x128 BK=32 linear LDS, 3D grid (8,32,3).
__global__ __launch_bounds__(256)
void qkv_gemm(const u16* __restrict__ A,
              const u16* __restrict__ wq, const u16* __restrict__ wk, const u16* __restrict__ wv,
              const float* __restrict__ bq, const float* __restrict__ bk, const float* __restrict__ bv,
              u16* __restrict__ Qb, u16* __restrict__ Kb, u16* __restrict__ VTb) {
    constexpr int Kd = GE;
    __shared__ u16 As[128 * 32];
    __shared__ u16 Bs[128 * 32];

    const int z = blockIdx.z;
    const u16* __restrict__ Bw = z == 0 ? wq : z == 1 ? wk : wv;
    const float* __restrict__ bias = z == 0 ? bq : z == 1 ? bk : bv;
    u16* __restrict__ outp = z == 0 ? Qb : z == 1 ? Kb : VTb;
    const float oscale = z == 0 ? SCQ : 1.0f;

    const int tid = threadIdx.x;
    const int m0 = blockIdx.y * 128;
    const int n0 = blockIdx.x * 128;
    const int wave = tid >> 6, lane = tid & 63;
    const int wm = (wave >> 1) * 64, wn = (wave & 1) * 64;
    const int g = lane >> 4, rw = lane & 15;

    f32x4 acc[4][4] = {};

    for (int kt = 0; kt < Kd; kt += 32) {
        __syncthreads();
#pragma unroll
        for (int j = 0; j < 2; ++j) {
            int c = wave * 128 + j * 64 + lane;      // chunk in [0,512)
            int r = c >> 2, u = (c & 3) * 8;
            gl_lds16(&A [(size_t)(m0 + r) * Kd + kt + u], &As[c * 8]);
            gl_lds16(&Bw[(size_t)(n0 + r) * Kd + kt + u], &Bs[c * 8]);
        }
        __syncthreads();

        bf16x8 aF[4], bF[4];
#pragma unroll
        for (int mf = 0; mf < 4; ++mf)
            aF[mf] = *reinterpret_cast<const bf16x8*>(&As[(wm + mf * 16 + rw) * 32 + g * 8]);
#pragma unroll
        for (int nf = 0; nf < 4; ++nf)
            bF[nf] = *reinterpret_cast<const bf16x8*>(&Bs[(wn + nf * 16 + rw) * 32 + g * 8]);
#pragma unroll
        for (int mf = 0; mf < 4; ++mf)
#pragma unroll
            for (int nf = 0; nf < 4; ++nf)
                acc[mf][nf] = __builtin_amdgcn_mfma_f32_16x16x32_bf16(aF[mf], bF[nf], acc[mf][nf], 0, 0, 0);
    }

#pragma unroll
    for (int mf = 0; mf < 4; ++mf)
#pragma unroll
        for (int nf = 0; nf < 4; ++nf)
#pragma unroll
            for (int r = 0; r < 4; ++r) {
                int m = m0 + wm + mf * 16 + g * 4 + r;
                int n = n0 + wn + nf * 16 + rw;
                u16 hv = f2bf((acc[mf][nf][r] + bias[n]) * oscale);
                int b = m >> 11, s = m & (GS - 1);
                int h = n >> 6, d = n & 63;
                if (z == 2)
                    outp[(((size_t)(b * GH + h)) * GD + d) * GS + s] = hv;
                else
                    outp[(((size_t)(b * GH + h)) * GS + s) * GD + d] = hv;
            }
}

// ---------------------------------------------------------------- out GEMM
// 128x64 tile, 2D grid (16,32) = 512 blocks (2/CU), no swizzle.
__global__ __launch_bounds__(256)
void out_gemm(const u16* __restrict__ A, const u16* __restrict__ Bw,
              const float* __restrict__ bias, float* __restrict__ outp) {
    constexpr int Kd = GE, Nd = GE;
    __shared__ u16 As[128 * 32];
    __shared__ u16 Bs[64 * 32];

    const int m0 = blockIdx.y * 128;
    const int n0 = blockIdx.x * 64;

    const int tid = threadIdx.x;
    const int wave = tid >> 6, lane = tid & 63;
    const int wm = (wave >> 1) * 64, wn = (wave & 1) * 32;
    const int g = lane >> 4, rw = lane & 15;

    f32x4 acc[4][2] = {};

    for (int kt = 0; kt < Kd; kt += 32) {
        __syncthreads();
        {
            int c = tid;
            int r = c >> 2, u = (c & 3) * 8;
            gl_lds16(&A [(size_t)(m0 + r) * Kd + kt + u], &As[c * 8]);
            int c2 = tid + 256;
            int r2 = c2 >> 2, u2 = (c2 & 3) * 8;
            gl_lds16(&A [(size_t)(m0 + r2) * Kd + kt + u2], &As[c2 * 8]);
            gl_lds16(&Bw[(size_t)(n0 + r) * Kd + kt + u], &Bs[c * 8]);
        }
        __syncthreads();

        bf16x8 aF[4], bF[2];
#pragma unroll
        for (int mf = 0; mf < 4; ++mf)
            aF[mf] = *reinterpret_cast<const bf16x8*>(&As[(wm + mf * 16 + rw) * 32 + g * 8]);
#pragma unroll
        for (int nf = 0; nf < 2; ++nf)
            bF[nf] = *reinterpret_cast<const bf16x8*>(&Bs[(wn + nf * 16 + rw) * 32 + g * 8]);
#pragma unroll
        for (int mf = 0; mf < 4; ++mf)
#pragma unroll
            for (int nf = 0; nf < 2; ++nf)
                acc[mf][nf] = __builtin_amdgcn_mfma_f32_16x16x32_bf16(aF[mf], bF[nf], acc[mf][nf], 0, 0, 0);
    }

#pragma unroll
    for (int mf = 0; mf < 4; ++mf)
#pragma unroll
        for (int nf = 0; nf < 2; ++nf)
#pragma unroll
            for (int r = 0; r < 4; ++r) {
                int m = m0 + wm + mf * 16 + g * 4 + r;
                int n = n0 + wn + nf * 16 + rw;
                outp[(size_t)m * Nd + n] = acc[mf][nf][r] + bias[n];
            }
}

// ---------------------------------------------------------------- attention
// R13: 8 waves x 32 q = 256 q-rows/block; KVBLK=128 (two 64-kv halves per
// barrier); double-buffered swizzled LDS (K tile 128x64, V tile 64x128).
template <int NSPLIT>
__global__ __launch_bounds__(512)
void attn_kernel(const u16* __restrict__ Q, const u16* __restrict__ Kp,
                 const u16* __restrict__ VT, u16* __restrict__ ctx,
                 float* __restrict__ Opart, float* __restrict__ Lpart) {
    int bh, qb, split;
    if (NSPLIT == 2) {
        const int wg = (blockIdx.x & 7) * 64 + (blockIdx.x >> 3);   // bijective, 512%8==0
        bh = wg >> 4;
        split = wg & 1;
        qb = ((wg >> 1) & 7) * 256;
    } else {
        const int wg = (blockIdx.x & 7) * 32 + (blockIdx.x >> 3);   // 256%8==0
        bh = wg >> 3;
        split = 0;
        qb = (wg & 7) * 256;
    }
    const int tid = threadIdx.x;
    const int wave = tid >> 6;      // 0..7
    const int lane = tid & 63;
    const int l31 = lane & 31;
    const int hi = (lane >> 5) & 1;
    const int q0 = qb + wave * 32;
    constexpr int KVLEN = GS / NSPLIT;
    constexpr int NT = KVLEN / 128;          // macro steps
    const int kvbase = split * KVLEN;

    const u16* __restrict__ Qbh = Q  + (size_t)bh * GS * GD;
    const u16* __restrict__ Kbh = Kp + (size_t)bh * GS * GD;
    const u16* __restrict__ Vbh = VT + (size_t)bh * GD * GS;

    __shared__ u16 sK[2][8192];
    __shared__ u16 sV[2][8192];

    bf16x8 qf[4];
#pragma unroll
    for (int s = 0; s < 4; ++s)
        qf[s] = *reinterpret_cast<const bf16x8*>(
            Qbh + (size_t)(q0 + l31) * GD + hi * 8 + 16 * s);

    f32x16 O0 = {}, O1 = {};
    float lsum = 0.f;

    const int kr0 = tid >> 3, kw0 = tid & 7;
    const u16* kSrc = Kbh + (size_t)(kvbase + kr0) * GD + ((kw0 ^ (kr0 & 7)) * 8);
    const int vr0 = tid >> 4, vw0 = tid & 15;
    const int vcol = ((vw0 & 8) | ((vw0 & 7) ^ (vr0 & 7))) * 8;
    const u16* vSrc = Vbh + (size_t)vr0 * GS + kvbase + vcol;
    u16* const dK0 = &sK[0][tid * 8];
    u16* const dK1 = &sK[1][tid * 8];
    u16* const dV0 = &sV[0][tid * 8];
    u16* const dV1 = &sV[1][tid * 8];

    auto stageTo = [&](u16* dk, u16* dv, const u16* ks, const u16* vs) {
        gl_lds16(ks,           dk);
        gl_lds16(ks + 64 * GD, dk + 4096);
        gl_lds16(vs,           dv);
        gl_lds16(vs + 32 * GS, dv + 4096);
    };

    int offK[4], offV[4];
#pragma unroll
    for (int s = 0; s < 4; ++s) {
        int sw = ((2 * s + hi) ^ (l31 & 7)) * 8;
        offK[s] = l31 * 64 + sw;
        offV[s] = l31 * 128 + sw;
    }

    auto half = [&](const u16* bK, const u16* bV) {
        f32x16 sa = {}, sb = {};
        bf16x8 ka[4], kb[4];
#pragma unroll
        for (int s = 0; s < 4; ++s) {
            ka[s] = *reinterpret_cast<const bf16x8*>(&bK[offK[s]]);
            kb[s] = *reinterpret_cast<const bf16x8*>(&bK[offK[s] + 2048]);
        }
        __builtin_amdgcn_s_setprio(1);
#pragma unroll
        for (int s = 0; s < 4; ++s) {
            sa = __builtin_amdgcn_mfma_f32_32x32x16_bf16(ka[s], qf[s], sa, 0, 0, 0);
            sb = __builtin_amdgcn_mfma_f32_32x32x16_bf16(kb[s], qf[s], sb, 0, 0, 0);
        }
        __builtin_amdgcn_s_setprio(0);

        bf16x8 vf0[4], vf1[4];
#pragma unroll
        for (int s = 0; s < 4; ++s) {
            vf0[s] = *reinterpret_cast<const bf16x8*>(&bV[offV[s]]);
            vf1[s] = *reinterpret_cast<const bf16x8*>(&bV[offV[s] + 4096]);
        }

        float pa[16], pb[16];
#pragma unroll
        for (int r = 0; r < 16; ++r) {
            pa[r] = __builtin_amdgcn_exp2f(sa[r]);
            pb[r] = __builtin_amdgcn_exp2f(sb[r]);
        }
        float s16[16];
#pragma unroll
        for (int r = 0; r < 16; ++r) s16[r] = pa[r] + pb[r];
#pragma unroll
        for (int r = 0; r < 8; ++r) s16[r] += s16[r + 8];
#pragma unroll
        for (int r = 0; r < 4; ++r) s16[r] += s16[r + 4];
        lsum += (s16[0] + s16[1]) + (s16[2] + s16[3]);

        u32 wa[8], wb[8];
#pragma unroll
        for (int i = 0; i < 8; ++i) {
            wa[i] = cvtpk(pa[2 * i], pa[2 * i + 1]);
            wb[i] = cvtpk(pb[2 * i], pb[2 * i + 1]);
        }
        plswap(wa[0], wa[2]); plswap(wa[1], wa[3]);
        plswap(wa[4], wa[6]); plswap(wa[5], wa[7]);
        plswap(wb[0], wb[2]); plswap(wb[1], wb[3]);
        plswap(wb[4], wb[6]); plswap(wb[5], wb[7]);
        u32x4 a0 = {wa[0], wa[1], wa[2], wa[3]};
        u32x4 a1 = {wa[4], wa[5], wa[6], wa[7]};
        u32x4 b0 = {wb[0], wb[1], wb[2], wb[3]};
        u32x4 b1 = {wb[4], wb[5], wb[6], wb[7]};
        bf16x8 pva0 = __builtin_bit_cast(bf16x8, a0);
        bf16x8 pva1 = __builtin_bit_cast(bf16x8, a1);
        bf16x8 pvb0 = __builtin_bit_cast(bf16x8, b0);
        bf16x8 pvb1 = __builtin_bit_cast(bf16x8, b1);

        __builtin_amdgcn_s_setprio(1);
        O0 = __builtin_amdgcn_mfma_f32_32x32x16_bf16(vf0[0], pva0, O0, 0, 0, 0);
        O0 = __builtin_amdgcn_mfma_f32_32x32x16_bf16(vf0[1], pva1, O0, 0, 0, 0);
        O0 = __builtin_amdgcn_mfma_f32_32x32x16_bf16(vf0[2], pvb0, O0, 0, 0, 0);
        O0 = __builtin_amdgcn_mfma_f32_32x32x16_bf16(vf0[3], pvb1, O0, 0, 0, 0);
        O1 = __builtin_amdgcn_mfma_f32_32x32x16_bf16(vf1[0], pva0, O1, 0, 0, 0);
        O1 = __builtin_amdgcn_mfma_f32_32x32x16_bf16(vf1[1], pva1, O1, 0, 0, 0);
        O1 = __builtin_amdgcn_mfma_f32_32x32x16_bf16(vf1[2], pvb0, O1, 0, 0, 0);
        O1 = __builtin_amdgcn_mfma_f32_32x32x16_bf16(vf1[3], pvb1, O1, 0, 0, 0);
        __builtin_amdgcn_s_setprio(0);
    };

    stageTo(dK0, dV0, kSrc, vSrc);
    kSrc += 128 * GD; vSrc += 128;
    __syncthreads();

#pragma unroll 1
    for (int t = 0; t < NT; t += 2) {
        stageTo(dK1, dV1, kSrc, vSrc);
        kSrc += 128 * GD; vSrc += 128;
        half(sK[0], sV[0]);
        half(sK[0] + 4096, sV[0] + 64);
        __syncthreads();
        if (t + 2 < NT) {
            stageTo(dK0, dV0, kSrc, vSrc);
            kSrc += 128 * GD; vSrc += 128;
        }
        half(sK[1], sV[1]);
        half(sK[1] + 4096, sV[1] + 64);
        __syncthreads();
    }

    lsum += xchg32(lsum);

    if (NSPLIT > 1) {
        const int wt = bh * 64 + (q0 >> 5);
        const size_t base = ((size_t)wt * NSPLIT + split) * PSTRIDE;
#pragma unroll
        for (int r = 0; r < 16; ++r) {
            int d = (r & 3) + 8 * (r >> 2) + 4 * hi;
            Opart[base + (size_t)d * 32 + l31]        = O0[r];
            Opart[base + (size_t)(d + 32) * 32 + l31] = O1[r];
        }
        if (hi == 0)
            Lpart[(wt * NSPLIT + split) * 32 + l31] = lsum;
    } else {
        const int bb = bh >> 4, h = bh & 15;
        const float inv = 1.0f / lsum;
        u16* crow = ctx + ((size_t)(bb * GS + q0 + l31)) * GE + h * 64;
#pragma unroll
        for (int g2 = 0; g2 < 4; ++g2) {
            ushort4 st0, st1;
            st0.x = f2bf(O0[4 * g2 + 0] * inv); st0.y = f2bf(O0[4 * g2 + 1] * inv);
            st0.z = f2bf(O0[4 * g2 + 2] * inv); st0.w = f2bf(O0[4 * g2 + 3] * inv);
            st1.x = f2bf(O1[4 * g2 + 0] * inv); st1.y = f2bf(O1[4 * g2 + 1] * inv);
            st1.z = f2bf(O1[4 * g2 + 2] * inv); st1.w = f2bf(O1[4 * g2 + 3] * inv);
            *reinterpret_cast<ushort4*>(crow + 8 * g2 + 4 * hi)      = st0;
            *reinterpret_cast<ushort4*>(crow + 32 + 8 * g2 + 4 * hi) = st1;
        }
    }
}

// ---------------------------------------------------------------- combine
template <int NSPLIT>
__global__ __launch_bounds__(256)
void combine_kernel(const float* __restrict__ Opart, const float* __restrict__ Lpart,
                    u16* __restrict__ ctx) {
    const int wt = blockIdx.x;
    const int bh = wt >> 6, bb = bh >> 4, h = bh & 15;
    const int q0 = (wt & 63) * 32;
    const int q = threadIdx.x & 31, db = threadIdx.x >> 5;
    const size_t b0 = (size_t)wt * NSPLIT * PSTRIDE;

    float lt = 0.f;
#pragma unroll
    for (int s = 0; s < NSPLIT; ++s) lt += Lpart[(wt * NSPLIT + s) * 32 + q];
    float inv = 1.f / lt;

    u16* crow = ctx + ((size_t)(bb * GS + q0 + q)) * GE + h * 64 + db * 8;
    ushort4 s0, s1;
    float o[8];
#pragma unroll
    for (int i = 0; i < 8; ++i) {
        int d = db * 8 + i;
        float acc = 0.f;
#pragma unroll
        for (int s = 0; s < NSPLIT; ++s)
            acc += Opart[b0 + (size_t)s * PSTRIDE + (size_t)d * 32 + q];
        o[i] = acc * inv;
    }
    s0.x = f2bf(o[0]); s0.y = f2bf(o[1]); s0.z = f2bf(o[2]); s0.w = f2bf(o[3]);
    s1.x = f2bf(o[4]); s1.y = f2bf(o[5]); s1.z = f2bf(o[6]); s1.w = f2bf(o[7]);
    *reinterpret_cast<ushort4*>(crow)     = s0;
    *reinterpret_cast<ushort4*>(crow + 4) = s1;
}

// ---------------------------------------------------------------- launcher
extern "C" void kernel_launch(void* const* d_in, const int* in_sizes, int n_in,
                              void* d_out, int out_size, void* d_ws, size_t ws_size,
                              hipStream_t stream) {
    (void)in_sizes; (void)n_in; (void)out_size;

    const float* x  = (const float*)d_in[0];
    const float* Wq = (const float*)d_in[1];
    const float* bq = (const float*)d_in[2];
    const float* Wk = (const float*)d_in[3];
    const float* bk = (const float*)d_in[4];
    const float* Wv = (const float*)d_in[5];
    const float* bv = (const float*)d_in[6];
    const float* Wo = (const float*)d_in[7];
    const float* bo = (const float*)d_in[8];
    float* out = (float*)d_out;

    char* ws = (char*)d_ws;
    u16* xb  = (u16*)(ws);                    // 8 MB  [4096,1024]
    u16* wqb = (u16*)(ws + (8ll  << 20));
    u16* wkb = (u16*)(ws + (10ll << 20));
    u16* wvb = (u16*)(ws + (12ll << 20));
    u16* wob = (u16*)(ws + (14ll << 20));
    u16* Qb  = (u16*)(ws + (16ll << 20));     // [B,H,S,D]
    u16* Kb  = (u16*)(ws + (24ll << 20));     // [B,H,S,D]
    u16* VTb = (u16*)(ws + (32ll << 20));     // [B,H,D,S]
    u16* ctx = (u16*)(ws + (40ll << 20));     // [B,S,E]
    float* Opart = (float*)(ws + (48ll << 20));   // 32 MB
    float* Lpart = (float*)(ws + (80ll << 20));
    const bool split2 = ws_size >= (81ll << 20);

    cvt_all<<<dim3(1024, 5), 256, 0, stream>>>(x, Wq, Wk, Wv, Wo,
                                               xb, wqb, wkb, wvb, wob);

    qkv_gemm<<<dim3(GE / 128, GM / 128, 3), 256, 0, stream>>>(
        xb, wqb, wkb, wvb, bq, bk, bv, Qb, Kb, VTb);

    if (split2) {
        attn_kernel<2><<<dim3(512), 512, 0, stream>>>(Qb, Kb, VTb, ctx, Opart, Lpart);
        combine_kernel<2><<<dim3(2048), 256, 0, stream>>>(Opart, Lpart, ctx);
    } else {
        attn_kernel<1><<<dim3(256), 512, 0, stream>>>(Qb, Kb, VTb, ctx, Opart, Lpart);
    }

    out_gemm<<<dim3(GE / 64, GM / 128), 256, 0, stream>>>(ctx, wob, bo, out);
}